// Round 2
// baseline (2138.632 us; speedup 1.0000x reference)
//
#include <hip/hip_runtime.h>
#include <stdint.h>

#define NB 8192
#define DIM 512

typedef __bf16 bf16x8 __attribute__((ext_vector_type(8)));
typedef float f32x4 __attribute__((ext_vector_type(4)));

__device__ __forceinline__ unsigned short f2bf(float x) {
  union { float f; unsigned u; } v; v.f = x;
  unsigned r = v.u + 0x7fff + ((v.u >> 16) & 1);
  return (unsigned short)(r >> 16);
}

// ---------------- prep: bf16 copy of rows + fp64 norm ----------------
__global__ __launch_bounds__(256)
void k_prep(const float* __restrict__ g, unsigned short* __restrict__ gb,
            float* __restrict__ rinvF, double* __restrict__ normD) {
  const int row = blockIdx.x;
  const int t = threadIdx.x;                 // 256 threads, 2 elems each
  const float2 v = ((const float2*)(g + (size_t)row * DIM))[t];
  ushort2 b; b.x = f2bf(v.x); b.y = f2bf(v.y);
  ((ushort2*)(gb + (size_t)row * DIM))[t] = b;
  double ss = (double)v.x * v.x + (double)v.y * v.y;
#pragma unroll
  for (int o = 32; o; o >>= 1) ss += __shfl_down(ss, o, 64);
  __shared__ double l[4];
  if ((t & 63) == 0) l[t >> 6] = ss;
  __syncthreads();
  if (t == 0) {
    double n = sqrt(l[0] + l[1] + l[2] + l[3]);
    if (n < 1e-12) n = 1e-12;
    normD[row] = n;
    rinvF[row] = (float)(1.0 / n);
  }
}

__global__ __launch_bounds__(256)
void k_cast(const float* __restrict__ s, unsigned short* __restrict__ d, int npairs) {
  int i = blockIdx.x * 256 + threadIdx.x;
  if (i < npairs) {
    float2 v = ((const float2*)s)[i];
    ushort2 b; b.x = f2bf(v.x); b.y = f2bf(v.y);
    ((ushort2*)d)[i] = b;
  }
}

// ---------------- bf16 GEMM, C = A @ B^T (A: MxK, B: NxK row-major) ----------------
template <bool SCALED>
__global__ __launch_bounds__(256, 2)
void k_gemm_bt(const unsigned short* __restrict__ A, const unsigned short* __restrict__ Bm,
               float* __restrict__ C, int M, int N, int K,
               const float* __restrict__ rowScale, const float* __restrict__ colScale,
               float mul) {
  __shared__ __align__(16) unsigned short lA[128 * 32];
  __shared__ __align__(16) unsigned short lB[128 * 32];
  const int tid = threadIdx.x;
  const int lane = tid & 63;
  const int wave = tid >> 6;
  const long brow = (long)blockIdx.y * 128;
  const long bcol = (long)blockIdx.x * 128;
  const int wrow = (wave >> 1) * 64;
  const int wcol = (wave & 1) * 64;

  f32x4 acc[4][4];
#pragma unroll
  for (int i = 0; i < 4; ++i)
#pragma unroll
    for (int j = 0; j < 4; ++j) acc[i][j] = (f32x4){0.f, 0.f, 0.f, 0.f};

  const int c0 = tid, c1 = tid + 256;
  const size_t aoff0 = (size_t)(brow + (c0 >> 2)) * K + (size_t)((c0 & 3) * 8);
  const size_t aoff1 = (size_t)(brow + (c1 >> 2)) * K + (size_t)((c1 & 3) * 8);
  const size_t boff0 = (size_t)(bcol + (c0 >> 2)) * K + (size_t)((c0 & 3) * 8);
  const size_t boff1 = (size_t)(bcol + (c1 >> 2)) * K + (size_t)((c1 & 3) * 8);

  for (int kb = 0; kb < K; kb += 32) {
    __builtin_amdgcn_global_load_lds(
        (const __attribute__((address_space(1))) void*)(A + aoff0 + kb),
        (__attribute__((address_space(3))) void*)(lA + c0 * 8), 16, 0, 0);
    __builtin_amdgcn_global_load_lds(
        (const __attribute__((address_space(1))) void*)(A + aoff1 + kb),
        (__attribute__((address_space(3))) void*)(lA + c1 * 8), 16, 0, 0);
    __builtin_amdgcn_global_load_lds(
        (const __attribute__((address_space(1))) void*)(Bm + boff0 + kb),
        (__attribute__((address_space(3))) void*)(lB + c0 * 8), 16, 0, 0);
    __builtin_amdgcn_global_load_lds(
        (const __attribute__((address_space(1))) void*)(Bm + boff1 + kb),
        (__attribute__((address_space(3))) void*)(lB + c1 * 8), 16, 0, 0);
    __syncthreads();

    const int fr = lane & 15;
    const int fk = (lane >> 4) * 8;
    bf16x8 af[4], bfr[4];
#pragma unroll
    for (int i = 0; i < 4; ++i)
      af[i] = *(const bf16x8*)(lA + (wrow + i * 16 + fr) * 32 + fk);
#pragma unroll
    for (int j = 0; j < 4; ++j)
      bfr[j] = *(const bf16x8*)(lB + (wcol + j * 16 + fr) * 32 + fk);
#pragma unroll
    for (int i = 0; i < 4; ++i)
#pragma unroll
      for (int j = 0; j < 4; ++j)
        acc[i][j] = __builtin_amdgcn_mfma_f32_16x16x32_bf16(af[i], bfr[j], acc[i][j], 0, 0, 0);
    __syncthreads();
  }

  const int lr = (lane >> 4) * 4;
  const int lc = lane & 15;
#pragma unroll
  for (int j = 0; j < 4; ++j) {
    const long gc = bcol + wcol + j * 16 + lc;
    float cs = mul;
    if (SCALED) cs *= colScale[gc];
#pragma unroll
    for (int i = 0; i < 4; ++i) {
      const long gr0 = brow + wrow + i * 16 + lr;
#pragma unroll
      for (int v = 0; v < 4; ++v) {
        const long gr = gr0 + v;
        float sc = cs;
        if (SCALED) sc *= rowScale[gr];
        C[(size_t)gr * N + gc] = acc[i][j][v] * sc;
      }
    }
  }
}

// ---------------- top-k helpers ----------------
template <int K>
__device__ __forceinline__ void topk_insert(float (&v)[K], int (&id)[K], float x, int ix) {
  if (x > v[K - 1]) {
    float nv = x; int ni = ix;
#pragma unroll
    for (int p = 0; p < K; ++p) {
      if (nv > v[p]) {
        float tv = v[p]; v[p] = nv; nv = tv;
        int ti = id[p]; id[p] = ni; ni = ti;
      }
    }
  }
}

// ---------------- row candidate top-16 (one block per row) ----------------
__global__ __launch_bounds__(256)
void k_cand_rows(const float* __restrict__ S, int* __restrict__ candOut) {
  const int row = blockIdx.x;
  const float* sr = S + (size_t)row * NB;
  const int t = threadIdx.x;
  float v[16]; int id[16];
#pragma unroll
  for (int i = 0; i < 16; ++i) { v[i] = -1e30f; id[i] = -1; }
  for (int j = t; j < NB; j += 256) topk_insert<16>(v, id, sr[j], j);

  __shared__ float lv[256 * 16];
  __shared__ int li[256 * 16];
#pragma unroll
  for (int i = 0; i < 16; ++i) { lv[t * 16 + i] = v[i]; li[t * 16 + i] = id[i]; }
  __syncthreads();
  for (int s = 128; s >= 1; s >>= 1) {
    if (t < s) {
      float mv[16]; int mi[16];
      int pa = 0, pb = 0;
#pragma unroll
      for (int i = 0; i < 16; ++i) {
        float va = lv[t * 16 + pa], vb = lv[(t + s) * 16 + pb];
        int ia = li[t * 16 + pa], ib = li[(t + s) * 16 + pb];
        bool ta = (va > vb) || (va == vb && ia <= ib);
        if (ta) { mv[i] = va; mi[i] = ia; ++pa; }
        else    { mv[i] = vb; mi[i] = ib; ++pb; }
      }
#pragma unroll
      for (int i = 0; i < 16; ++i) { lv[t * 16 + i] = mv[i]; li[t * 16 + i] = mi[i]; }
    }
    __syncthreads();
  }
  if (t < 16) candOut[row * 16 + t] = li[t];
}

// ---------------- column candidates: chunked partial top-8 + merge to 16 ----------------
__global__ __launch_bounds__(256)
void k_topk_cols_part(const float* __restrict__ S, float* __restrict__ candV,
                      int* __restrict__ candI) {
  const int col = blockIdx.x * 256 + threadIdx.x;
  const int chunk = blockIdx.y;               // 8 chunks of 1024 rows
  const int r0 = chunk * 1024;
  float v[8]; int id[8];
#pragma unroll
  for (int i = 0; i < 8; ++i) { v[i] = -1e30f; id[i] = -1; }
  const float* p = S + (size_t)r0 * NB + col;
#pragma unroll 4
  for (int i = 0; i < 1024; ++i) topk_insert<8>(v, id, p[(size_t)i * NB], r0 + i);
  const size_t base = ((size_t)col * 8 + chunk) * 8;
#pragma unroll
  for (int i = 0; i < 8; ++i) { candV[base + i] = v[i]; candI[base + i] = id[i]; }
}

__global__ __launch_bounds__(256)
void k_cand_cols(const float* __restrict__ candV, const int* __restrict__ candI,
                 int* __restrict__ candOut) {
  const int col = blockIdx.x * 256 + threadIdx.x;
  float v[16]; int id[16];
#pragma unroll
  for (int i = 0; i < 16; ++i) { v[i] = -1e30f; id[i] = -1; }
  const size_t base = (size_t)col * 64;
  for (int c = 0; c < 64; ++c) topk_insert<16>(v, id, candV[base + c], candI[base + c]);
#pragma unroll
  for (int i = 0; i < 16; ++i) candOut[col * 16 + i] = id[i];
}

// ---------------- exact fp64 rescore of 16 candidates -> top-8 + softmax ----------------
__global__ __launch_bounds__(256)
void k_rescore(const float* __restrict__ Xq, const float* __restrict__ Xc,
               const double* __restrict__ nQ, const double* __restrict__ nC,
               const int* __restrict__ cand, int* __restrict__ idxOut,
               float* __restrict__ wOut) {
  const int r = blockIdx.x;
  const int t = threadIdx.x;
  __shared__ float q[DIM];
  __shared__ double sc[16];
  __shared__ int sidx[16];
  const float2 qv = ((const float2*)(Xq + (size_t)r * DIM))[t];
  q[2 * t] = qv.x; q[2 * t + 1] = qv.y;
  if (t < 16) sidx[t] = cand[r * 16 + t];
  __syncthreads();
  const int wave = t >> 6, lane = t & 63;
  for (int c = wave; c < 16; c += 4) {
    const float* xr = Xc + (size_t)sidx[c] * DIM;
    double acc = 0.0;
    for (int j = lane; j < DIM; j += 64) acc += (double)q[j] * (double)xr[j];
#pragma unroll
    for (int o = 32; o; o >>= 1) acc += __shfl_down(acc, o, 64);
    if (lane == 0) sc[c] = acc;
  }
  __syncthreads();
  if (t == 0) {
    const double nq = nQ[r];
    double s[16]; int id[16];
#pragma unroll
    for (int i = 0; i < 16; ++i) {
      id[i] = sidx[i];
      s[i] = sc[i] / (nq * nC[sidx[i]]) * 5.0;   // /tau, tau=0.2
    }
    // insertion sort: descending score, ascending index on ties
    for (int i = 1; i < 16; ++i) {
      double sv = s[i]; int iv = id[i]; int j = i - 1;
      while (j >= 0 && (s[j] < sv || (s[j] == sv && id[j] > iv))) {
        s[j + 1] = s[j]; id[j + 1] = id[j]; --j;
      }
      s[j + 1] = sv; id[j + 1] = iv;
    }
    double m = s[0], e[8], sum = 0.0;
#pragma unroll
    for (int i = 0; i < 8; ++i) { e[i] = exp(s[i] - m); sum += e[i]; }
    const double inv = 1.0 / sum;
#pragma unroll
    for (int i = 0; i < 8; ++i) {
      idxOut[r * 8 + i] = id[i];
      wOut[r * 8 + i] = (float)(e[i] * inv);
    }
  }
}

// ---------------- gather message + residual + LayerNorm ----------------
__global__ __launch_bounds__(256)
void k_msg_ln(const float* __restrict__ g, const float* __restrict__ P,
              const int* __restrict__ idx, const float* __restrict__ w,
              const float* __restrict__ gamma, const float* __restrict__ beta,
              float* __restrict__ out) {
  const int row = blockIdx.x;
  const int t = threadIdx.x;                  // 256 threads, 2 elems each
  __shared__ int sidx[8];
  __shared__ float sw[8];
  if (t < 8) { sidx[t] = idx[row * 8 + t]; sw[t] = w[row * 8 + t]; }
  __syncthreads();
  float mx = 0.f, my = 0.f;
#pragma unroll
  for (int k = 0; k < 8; ++k) {
    const float2 pv = ((const float2*)(P + (size_t)sidx[k] * DIM))[t];
    mx += sw[k] * pv.x; my += sw[k] * pv.y;
  }
  const float2 gv = ((const float2*)(g + (size_t)row * DIM))[t];
  const float x0 = gv.x + 0.3f * mx;
  const float x1 = gv.y + 0.3f * my;
  float s = x0 + x1, ss = x0 * x0 + x1 * x1;
#pragma unroll
  for (int o = 32; o; o >>= 1) { s += __shfl_down(s, o, 64); ss += __shfl_down(ss, o, 64); }
  __shared__ float ls[4], lss[4];
  if ((t & 63) == 0) { ls[t >> 6] = s; lss[t >> 6] = ss; }
  __syncthreads();
  const float tot = ls[0] + ls[1] + ls[2] + ls[3];
  const float tots = lss[0] + lss[1] + lss[2] + lss[3];
  const float mu = tot * (1.0f / DIM);
  const float var = tots * (1.0f / DIM) - mu * mu;
  const float rstd = rsqrtf(var + 1e-5f);
  const float2 gm = ((const float2*)gamma)[t];
  const float2 bt = ((const float2*)beta)[t];
  float2 o2;
  o2.x = (x0 - mu) * rstd * gm.x + bt.x;
  o2.y = (x1 - mu) * rstd * gm.y + bt.y;
  ((float2*)(out + (size_t)row * DIM))[t] = o2;
}

extern "C" void kernel_launch(void* const* d_in, const int* in_sizes, int n_in,
                              void* d_out, int out_size, void* d_ws, size_t ws_size,
                              hipStream_t stream) {
  const float* gI = (const float*)d_in[0];
  const float* gT = (const float*)d_in[1];
  const float* Wi = (const float*)d_in[2];
  const float* Wt = (const float*)d_in[3];
  const float* gamma_i = (const float*)d_in[4];
  const float* beta_i  = (const float*)d_in[5];
  const float* gamma_t = (const float*)d_in[6];
  const float* beta_t  = (const float*)d_in[7];

  float* outI = (float*)d_out;
  float* outT = outI + (size_t)NB * DIM;
  float* S    = outT + (size_t)NB * DIM;

  // workspace carve-up (byte cursor, 16B aligned)
  char* wsb = (char*)d_ws;
  size_t off = 0;
  auto alloc = [&](size_t bytes) -> void* {
    off = (off + 15) & ~(size_t)15;
    void* p = wsb + off;
    off += bytes;
    return p;
  };
  unsigned short* gIb = (unsigned short*)alloc((size_t)NB * DIM * 2);
  unsigned short* gTb = (unsigned short*)alloc((size_t)NB * DIM * 2);
  unsigned short* Wib = (unsigned short*)alloc((size_t)DIM * DIM * 2);
  unsigned short* Wtb = (unsigned short*)alloc((size_t)DIM * DIM * 2);
  float* rinvI = (float*)alloc((size_t)NB * 4);
  float* rinvT = (float*)alloc((size_t)NB * 4);
  double* normI = (double*)alloc((size_t)NB * 8);
  double* normT = (double*)alloc((size_t)NB * 8);
  float* Pt = (float*)alloc((size_t)NB * DIM * 4);
  float* Pi = (float*)alloc((size_t)NB * DIM * 4);
  float* candV = (float*)alloc((size_t)NB * 64 * 4);
  int*   candI = (int*)alloc((size_t)NB * 64 * 4);
  int*   candRow = (int*)alloc((size_t)NB * 16 * 4);
  int*   candCol = (int*)alloc((size_t)NB * 16 * 4);
  int*   idx_it = (int*)alloc((size_t)NB * 8 * 4);
  float* w_it   = (float*)alloc((size_t)NB * 8 * 4);
  int*   idx_ti = (int*)alloc((size_t)NB * 8 * 4);
  float* w_ti   = (float*)alloc((size_t)NB * 8 * 4);

  k_prep<<<NB, 256, 0, stream>>>(gI, gIb, rinvI, normI);
  k_prep<<<NB, 256, 0, stream>>>(gT, gTb, rinvT, normT);
  k_cast<<<(DIM * DIM / 2 + 255) / 256, 256, 0, stream>>>(Wi, Wib, DIM * DIM / 2);
  k_cast<<<(DIM * DIM / 2 + 255) / 256, 256, 0, stream>>>(Wt, Wtb, DIM * DIM / 2);

  // S = (gi . gt^T)/tau, scaled in epilogue by rinvI[i]*rinvT[j]*5
  k_gemm_bt<true><<<dim3(NB / 128, NB / 128), 256, 0, stream>>>(
      gIb, gTb, S, NB, NB, DIM, rinvI, rinvT, 5.0f);
  // Pt = gT @ Wt^T ; Pi = gI @ Wi^T
  k_gemm_bt<false><<<dim3(DIM / 128, NB / 128), 256, 0, stream>>>(
      gTb, Wtb, Pt, NB, DIM, DIM, nullptr, nullptr, 1.0f);
  k_gemm_bt<false><<<dim3(DIM / 128, NB / 128), 256, 0, stream>>>(
      gIb, Wib, Pi, NB, DIM, DIM, nullptr, nullptr, 1.0f);

  // candidates from bf16 S
  k_cand_rows<<<NB, 256, 0, stream>>>(S, candRow);
  k_topk_cols_part<<<dim3(NB / 256, 8), 256, 0, stream>>>(S, candV, candI);
  k_cand_cols<<<NB / 256, 256, 0, stream>>>(candV, candI, candCol);

  // exact fp64 rescore -> final top-8 + weights
  k_rescore<<<NB, 256, 0, stream>>>(gI, gT, normI, normT, candRow, idx_it, w_it);
  k_rescore<<<NB, 256, 0, stream>>>(gT, gI, normT, normI, candCol, idx_ti, w_ti);

  k_msg_ln<<<NB, 256, 0, stream>>>(gI, Pt, idx_it, w_it, gamma_i, beta_i, outI);
  k_msg_ln<<<NB, 256, 0, stream>>>(gT, Pi, idx_ti, w_ti, gamma_t, beta_t, outT);
}